// Round 12
// baseline (350.189 us; speedup 1.0000x reference)
//
#include <hip/hip_runtime.h>
#include <stdint.h>

// PointerNetwork forward, MI355X/gfx950.
// R21: R20 won (280us; k3 ~105 after exp-factorization). kA_front=116 is
// now the top kernel. Its known defect: P2's 96-float/thread weights >
// the proven ~32-48-float residency limit => ~12.6MB/block L2 refetch.
// Fix (R17's k2 idea, but INSIDE kA where GI is already in LDS): P2 at
// 1024 threads — thr 0-511 r-gate rows (32-fl resident), 512-1023 z-gate
// rows (32-fl), all threads a 16-fl n-gate slice; partials via GT[384]
// LDS; combine on thr 0-127 with GI prefetched at loop top. P0 re-split
// 128x8 (16-fl slice), P1 output-stationary acc[3][8]. launch_bounds
// (1024,4) => truthful 4 waves/EU => 128-VGPR budget, demand ~110.
// k3 + mega fallback byte-identical to R20.
// B=256, S=64, H=128.

#define BN 256
#define SN 64
#define HN 128
#define NEGV (-1.0e9f)
#define TINYF 1.17549435e-38f

// k3 LDS layout (floats)
#define OFF_A   0
#define OFF_GI  8192
#define OFF_WHC 8192
#define OFF_SET 16384
#define OFF_UT  24832
#define OFF_HC  33280
#define OFF_KK  33536
#define OFF_SV  33664
#define OFF_DY  33792
#define OFF_WD  33920
#define OFF_CV  34176
#define OFF_VS  34304       // Vsum scalar
#define SMEM_FLOATS 34308   // 137232 B

// kA LDS layout (floats)
#define KA_A   0           // 8192: X history
#define KA_GI  8192        // 64 x 384
#define KA_HC  32768       // 256: x/h dbuf
#define KA_GT  33024       // 384: gate partials
#define KA_FLOATS 33408    // 133632 B

// ws layout (floats): [0,256) Wd, [256,384) cv (fallback only), Hg at 384
#define WS_HG   384
#define WS_NEED ((size_t)(384 + 256 * 64 * 128) * 4)

typedef float v4f __attribute__((ext_vector_type(4)));

struct W8 { v4f a, b, c, d, e, f, g, h; };

// 8 x dwordx4 at 64B stride (32 floats of a 4-way k-split row).
__device__ __forceinline__ W8 ldg8_s64(const float* p) {
  W8 r;
  asm volatile(
      "global_load_dwordx4 %0, %8, off\n\t"
      "global_load_dwordx4 %1, %8, off offset:64\n\t"
      "global_load_dwordx4 %2, %8, off offset:128\n\t"
      "global_load_dwordx4 %3, %8, off offset:192\n\t"
      "global_load_dwordx4 %4, %8, off offset:256\n\t"
      "global_load_dwordx4 %5, %8, off offset:320\n\t"
      "global_load_dwordx4 %6, %8, off offset:384\n\t"
      "global_load_dwordx4 %7, %8, off offset:448\n\t"
      "s_waitcnt vmcnt(0)"
      : "=&v"(r.a), "=&v"(r.b), "=&v"(r.c), "=&v"(r.d),
        "=&v"(r.e), "=&v"(r.f), "=&v"(r.g), "=&v"(r.h)
      : "v"(p));
  return r;
}

__device__ __forceinline__ float dot8(const W8& w, const float4* x4) {
  float a0 = 0.f, a1 = 0.f, a2 = 0.f, a3 = 0.f;
  a0 = fmaf(w.a.x, x4[0].x, a0); a1 = fmaf(w.a.y, x4[0].y, a1);
  a2 = fmaf(w.a.z, x4[0].z, a2); a3 = fmaf(w.a.w, x4[0].w, a3);
  a0 = fmaf(w.b.x, x4[1].x, a0); a1 = fmaf(w.b.y, x4[1].y, a1);
  a2 = fmaf(w.b.z, x4[1].z, a2); a3 = fmaf(w.b.w, x4[1].w, a3);
  a0 = fmaf(w.c.x, x4[2].x, a0); a1 = fmaf(w.c.y, x4[2].y, a1);
  a2 = fmaf(w.c.z, x4[2].z, a2); a3 = fmaf(w.c.w, x4[2].w, a3);
  a0 = fmaf(w.d.x, x4[3].x, a0); a1 = fmaf(w.d.y, x4[3].y, a1);
  a2 = fmaf(w.d.z, x4[3].z, a2); a3 = fmaf(w.d.w, x4[3].w, a3);
  a0 = fmaf(w.e.x, x4[4].x, a0); a1 = fmaf(w.e.y, x4[4].y, a1);
  a2 = fmaf(w.e.z, x4[4].z, a2); a3 = fmaf(w.e.w, x4[4].w, a3);
  a0 = fmaf(w.f.x, x4[5].x, a0); a1 = fmaf(w.f.y, x4[5].y, a1);
  a2 = fmaf(w.f.z, x4[5].z, a2); a3 = fmaf(w.f.w, x4[5].w, a3);
  a0 = fmaf(w.g.x, x4[6].x, a0); a1 = fmaf(w.g.y, x4[6].y, a1);
  a2 = fmaf(w.g.z, x4[6].z, a2); a3 = fmaf(w.g.w, x4[6].w, a3);
  a0 = fmaf(w.h.x, x4[7].x, a0); a1 = fmaf(w.h.y, x4[7].y, a1);
  a2 = fmaf(w.h.z, x4[7].z, a2); a3 = fmaf(w.h.w, x4[7].w, a3);
  return (a0 + a1) + (a2 + a3);
}

__device__ __forceinline__ uint32_t rotl32(uint32_t v, int d) {
  return (v << d) | (v >> (32 - d));
}

__device__ __forceinline__ void threefry2x32(uint32_t k0, uint32_t k1,
                                             uint32_t x0, uint32_t x1,
                                             uint32_t& o0, uint32_t& o1) {
  uint32_t ks2 = k0 ^ k1 ^ 0x1BD11BDAu;
  x0 += k0; x1 += k1;
  x0 += x1; x1 = rotl32(x1, 13); x1 ^= x0;
  x0 += x1; x1 = rotl32(x1, 15); x1 ^= x0;
  x0 += x1; x1 = rotl32(x1, 26); x1 ^= x0;
  x0 += x1; x1 = rotl32(x1, 6);  x1 ^= x0;
  x0 += k1; x1 += ks2 + 1u;
  x0 += x1; x1 = rotl32(x1, 17); x1 ^= x0;
  x0 += x1; x1 = rotl32(x1, 29); x1 ^= x0;
  x0 += x1; x1 = rotl32(x1, 16); x1 ^= x0;
  x0 += x1; x1 = rotl32(x1, 24); x1 ^= x0;
  x0 += ks2; x1 += k0 + 2u;
  x0 += x1; x1 = rotl32(x1, 13); x1 ^= x0;
  x0 += x1; x1 = rotl32(x1, 15); x1 ^= x0;
  x0 += x1; x1 = rotl32(x1, 26); x1 ^= x0;
  x0 += x1; x1 = rotl32(x1, 6);  x1 ^= x0;
  x0 += k0; x1 += k1 + 3u;
  x0 += x1; x1 = rotl32(x1, 17); x1 ^= x0;
  x0 += x1; x1 = rotl32(x1, 29); x1 ^= x0;
  x0 += x1; x1 = rotl32(x1, 16); x1 ^= x0;
  x0 += x1; x1 = rotl32(x1, 24); x1 ^= x0;
  x0 += k1; x1 += ks2 + 4u;
  x0 += x1; x1 = rotl32(x1, 13); x1 ^= x0;
  x0 += x1; x1 = rotl32(x1, 15); x1 ^= x0;
  x0 += x1; x1 = rotl32(x1, 26); x1 ^= x0;
  x0 += x1; x1 = rotl32(x1, 6);  x1 ^= x0;
  x0 += ks2; x1 += k0 + 5u;
  o0 = x0; o1 = x1;
}

__device__ __forceinline__ float jax_gumbel(uint32_t k0, uint32_t k1, int j) {
  uint32_t o0, o1;
  threefry2x32(k0, k1, 0u, (uint32_t)j, o0, o1);
  uint32_t bits = o0 ^ o1;
  uint32_t ub = (bits >> 9) | 0x3F800000u;
  float u = __uint_as_float(ub) - 1.0f;
  u = fmaxf(u + TINYF, TINYF);
  return -logf(-logf(u));
}

// tanh(x) = (e^{2x}-1)/(e^{2x}+1).
__device__ __forceinline__ float ftanh(float x) {
  float e = __expf(2.0f * x);
  return (e - 1.0f) * __builtin_amdgcn_rcpf(e + 1.0f);
}

__device__ __forceinline__ float fsig(float x) {
  return __builtin_amdgcn_rcpf(1.0f + __expf(-x));
}

// ---------------- K0 (fallback path only) ----------------
__global__ void k0_dyn(const float* __restrict__ W_att, const float* __restrict__ dyn_w,
                       const float* __restrict__ dyn_b, float* __restrict__ Wd,
                       float* __restrict__ cv) {
  int h = threadIdx.x;
  float w0 = 0.f, w1 = 0.f, cc = 0.f;
  for (int k = 0; k < HN; ++k) {
    float w = W_att[h * 384 + 128 + k];
    w0 = fmaf(w, dyn_w[2 * k + 0], w0);
    w1 = fmaf(w, dyn_w[2 * k + 1], w1);
    cc = fmaf(w, dyn_b[k], cc);
  }
  Wd[2 * h] = w0; Wd[2 * h + 1] = w1; cv[h] = cc;
}

// ---------------- kA: P0 + P1 + P2 at 1024 thr, residency-safe ----------------
__global__ __launch_bounds__(1024, 4)
void kA_front(const float* __restrict__ SE, const float* __restrict__ in_w,
              const float* __restrict__ in_b, const float* __restrict__ w_ih,
              const float* __restrict__ b_ih, const float* __restrict__ w_hh,
              const float* __restrict__ b_hh, float* __restrict__ Hg) {
  extern __shared__ float sm[];
  float* A   = sm + KA_A;
  float* GIl = sm + KA_GI;
  float* HC  = sm + KA_HC;
  float* GT  = sm + KA_GT;
  int b = blockIdx.x, t = threadIdx.x;

  if (t < 128) HC[t] = SE[b * 8192 + t * 64];   // x_{-1} = SE[b,:,0]
  __syncthreads();

  // P0: x-chain. 128 ml x 8 ks (16-fl resident slice, contiguous)
  {
    int ml = t >> 3, ks = t & 7;
    const float* wp = in_w + ml * HN + ks * 16;
    float4 w0 = *(const float4*)(wp);
    float4 w1 = *(const float4*)(wp + 4);
    float4 w2 = *(const float4*)(wp + 8);
    float4 w3 = *(const float4*)(wp + 12);
    float bib = in_b[ml];
    for (int ii = 0; ii < SN; ++ii) {
      const float* xc = HC + (ii & 1) * 128;
      float* xn = HC + ((ii + 1) & 1) * 128;
      float4 x0 = *(const float4*)(xc + ks * 16);
      float4 x1 = *(const float4*)(xc + ks * 16 + 4);
      float4 x2 = *(const float4*)(xc + ks * 16 + 8);
      float4 x3 = *(const float4*)(xc + ks * 16 + 12);
      float a0 = 0.f, a1 = 0.f;
      a0 = fmaf(w0.x, x0.x, a0); a1 = fmaf(w0.y, x0.y, a1);
      a0 = fmaf(w0.z, x0.z, a0); a1 = fmaf(w0.w, x0.w, a1);
      a0 = fmaf(w1.x, x1.x, a0); a1 = fmaf(w1.y, x1.y, a1);
      a0 = fmaf(w1.z, x1.z, a0); a1 = fmaf(w1.w, x1.w, a1);
      a0 = fmaf(w2.x, x2.x, a0); a1 = fmaf(w2.y, x2.y, a1);
      a0 = fmaf(w2.z, x2.z, a0); a1 = fmaf(w2.w, x2.w, a1);
      a0 = fmaf(w3.x, x3.x, a0); a1 = fmaf(w3.y, x3.y, a1);
      a0 = fmaf(w3.z, x3.z, a0); a1 = fmaf(w3.w, x3.w, a1);
      float s = a0 + a1;
      s += __shfl_xor(s, 1); s += __shfl_xor(s, 2); s += __shfl_xor(s, 4);
      if (ks == 0) {
        float xv = s + bib;
        A[ii * 128 + ml] = xv;
        xn[ml] = xv;
      }
      __syncthreads();
    }
  }

  // P1: GI = w_ih @ X + b_ih, output-stationary over k. 128 r x 8 cg.
  {
    int r = t & 127, cg = t >> 7;
    const float* xb = A + cg * 8 * 128;
    const float* w0p = w_ih + (r)       * HN;
    const float* w1p = w_ih + (r + 128) * HN;
    const float* w2p = w_ih + (r + 256) * HN;
    float acc[3][8];
#pragma unroll
    for (int g = 0; g < 3; ++g)
#pragma unroll
      for (int i = 0; i < 8; ++i) acc[g][i] = 0.f;
#pragma unroll 1
    for (int k = 0; k < HN; k += 4) {
      float4 w0 = *(const float4*)(w0p + k);
      float4 w1 = *(const float4*)(w1p + k);
      float4 w2 = *(const float4*)(w2p + k);
#pragma unroll
      for (int i = 0; i < 8; ++i) {
        float4 xv = *(const float4*)(xb + i * 128 + k);   // broadcast
        acc[0][i] = fmaf(w0.x, xv.x, acc[0][i]);
        acc[0][i] = fmaf(w0.y, xv.y, acc[0][i]);
        acc[0][i] = fmaf(w0.z, xv.z, acc[0][i]);
        acc[0][i] = fmaf(w0.w, xv.w, acc[0][i]);
        acc[1][i] = fmaf(w1.x, xv.x, acc[1][i]);
        acc[1][i] = fmaf(w1.y, xv.y, acc[1][i]);
        acc[1][i] = fmaf(w1.z, xv.z, acc[1][i]);
        acc[1][i] = fmaf(w1.w, xv.w, acc[1][i]);
        acc[2][i] = fmaf(w2.x, xv.x, acc[2][i]);
        acc[2][i] = fmaf(w2.y, xv.y, acc[2][i]);
        acc[2][i] = fmaf(w2.z, xv.z, acc[2][i]);
        acc[2][i] = fmaf(w2.w, xv.w, acc[2][i]);
      }
    }
    float b0 = b_ih[r], b1 = b_ih[r + 128], b2 = b_ih[r + 256];
#pragma unroll
    for (int i = 0; i < 8; ++i) {
      int n = cg * 8 + i;
      GIl[n * 384 + r]       = acc[0][i] + b0;
      GIl[n * 384 + 128 + r] = acc[1][i] + b1;
      GIl[n * 384 + 256 + r] = acc[2][i] + b2;
    }
    __syncthreads();
  }

  // P2: GRU chain, residency-safe split.
  //   thr 0-511: r-gate rows (g=0), thr 512-1023: z-gate rows (g=1),
  //   each 128 ml x 4 ks = 32-fl resident slice (proven size).
  //   ALL threads: n-gate 16-fl slice (128 mln x 8 ksn).
  if (t < 256) HC[t] = 0.f;
  __syncthreads();
  {
    int g = t >> 9;              // 0: reset rows, 1: update rows
    int ml = (t >> 2) & 127;
    int ks = t & 3;
    int row = g * 128 + ml;
    int mln = t >> 3;            // 0..127
    int ksn = t & 7;

    W8 wv = ldg8_s64(w_hh + row * HN + ks * 4);   // 32-fl resident (r/z)
    float brz = b_hh[row];
    const float* wnp = w_hh + (256 + mln) * HN + ksn * 16;
    float4 wn0 = *(const float4*)(wnp);           // 16-fl n-slice
    float4 wn1 = *(const float4*)(wnp + 4);
    float4 wn2 = *(const float4*)(wnp + 8);
    float4 wn3 = *(const float4*)(wnp + 12);
    float bn = b_hh[256 + mln];

    float hp = 0.f;
    for (int ii = 0; ii < SN; ++ii) {
      const float* hc = HC + (ii & 1) * 128;
      float* hw = HC + ((ii + 1) & 1) * 128;
      float gi0 = 0.f, gi1 = 0.f, gi2 = 0.f;
      if (t < 128) {                     // prefetch GI; used post-barrier
        const float* gr = GIl + ii * 384;
        gi0 = gr[t]; gi1 = gr[128 + t]; gi2 = gr[256 + t];
      }
      // r/z dot (4-way strided slice)
      float4 x4[8];
#pragma unroll
      for (int q = 0; q < 8; ++q)
        x4[q] = *(const float4*)(hc + q * 16 + ks * 4);
      float s = dot8(wv, x4);
      s += __shfl_xor(s, 1); s += __shfl_xor(s, 2);
      // n dot (contiguous 16)
      float4 y0 = *(const float4*)(hc + ksn * 16);
      float4 y1 = *(const float4*)(hc + ksn * 16 + 4);
      float4 y2 = *(const float4*)(hc + ksn * 16 + 8);
      float4 y3 = *(const float4*)(hc + ksn * 16 + 12);
      float n0 = 0.f, n1 = 0.f;
      n0 = fmaf(wn0.x, y0.x, n0); n1 = fmaf(wn0.y, y0.y, n1);
      n0 = fmaf(wn0.z, y0.z, n0); n1 = fmaf(wn0.w, y0.w, n1);
      n0 = fmaf(wn1.x, y1.x, n0); n1 = fmaf(wn1.y, y1.y, n1);
      n0 = fmaf(wn1.z, y1.z, n0); n1 = fmaf(wn1.w, y1.w, n1);
      n0 = fmaf(wn2.x, y2.x, n0); n1 = fmaf(wn2.y, y2.y, n1);
      n0 = fmaf(wn2.z, y2.z, n0); n1 = fmaf(wn2.w, y2.w, n1);
      n0 = fmaf(wn3.x, y3.x, n0); n1 = fmaf(wn3.y, y3.y, n1);
      n0 = fmaf(wn3.z, y3.z, n0); n1 = fmaf(wn3.w, y3.w, n1);
      float sn = n0 + n1;
      sn += __shfl_xor(sn, 1); sn += __shfl_xor(sn, 2); sn += __shfl_xor(sn, 4);

      if (ks == 0)  GT[row] = s + brz;
      if (ksn == 0) GT[256 + mln] = sn + bn;
      __syncthreads();

      if (t < 128) {
        float r = fsig(gi0 + GT[t]);
        float z = fsig(gi1 + GT[128 + t]);
        float nn = ftanh(gi2 + r * GT[256 + t]);
        float hn = (1.0f - z) * nn + z * hp;
        hw[t] = hn;
        Hg[b * 8192 + ii * 128 + t] = hn;
        hp = hn;
      }
      __syncthreads();
    }
  }
}

// ---------------- k3: P3..P8 at 1024 threads; exp-factored P6 ----------------
__global__ __launch_bounds__(1024)
void k3_att(const float* __restrict__ SE, const float* __restrict__ dynamic,
            const float* __restrict__ dyn_w, const float* __restrict__ dyn_b,
            const float* __restrict__ W_att, const float* __restrict__ v_att,
            const float* __restrict__ Hg, float* __restrict__ out) {
  extern __shared__ float sm[];
  int b = blockIdx.x, t = threadIdx.x;
  float* A   = sm + OFF_A;
  float* WHC = sm + OFF_WHC;
  float* SET = sm + OFF_SET;
  float* UT  = sm + OFF_UT;
  uint32_t* KK = (uint32_t*)(sm + OFF_KK);
  float* SV  = sm + OFF_SV;
  float* DY  = sm + OFF_DY;
  float* WDs = sm + OFF_WD;
  float* CVs = sm + OFF_CV;

  // staging: dyn-fold on 512 thr; SV (pre-doubled), DY; keys; Vsum wave
  if (t < 512) {
    int h = t >> 2, ks2 = t & 3;
    const float* wp = W_att + h * 384 + 128 + ks2 * 32;
    float w0 = 0.f, w1 = 0.f, cc = 0.f;
    for (int k = 0; k < 32; ++k) {
      float w = wp[k];
      int kk = ks2 * 32 + k;
      w0 = fmaf(w, dyn_w[2 * kk + 0], w0);
      w1 = fmaf(w, dyn_w[2 * kk + 1], w1);
      cc = fmaf(w, dyn_b[kk], cc);
    }
    w0 += __shfl_xor(w0, 1); w0 += __shfl_xor(w0, 2);
    w1 += __shfl_xor(w1, 1); w1 += __shfl_xor(w1, 2);
    cc += __shfl_xor(cc, 1); cc += __shfl_xor(cc, 2);
    if (ks2 == 0) { WDs[2 * h] = w0; WDs[2 * h + 1] = w1; CVs[h] = cc; }
  } else if (t < 640) {
    int tt = t - 512;
    SV[tt] = 2.0f * v_att[tt];          // pre-doubled for the rcp form
    DY[tt] = dynamic[b * 128 + tt];
  } else if (t < 704) {
    int tt = t - 640;
    uint32_t o0, o1;
    threefry2x32(0u, 42u, 0u, (uint32_t)tt, o0, o1);
    KK[2 * tt] = o0; KK[2 * tt + 1] = o1;
  } else if (t < 768) {
    int tt = t - 704;                   // one full wave: Vsum = sum(v_att)
    float v = v_att[tt] + v_att[tt + 64];
#pragma unroll
    for (int off = 32; off > 0; off >>= 1) v += __shfl_xor(v, off);
    if (tt == 0) sm[OFF_VS] = v;
  }
  for (int p = 0; p < 8; ++p)
    A[p * 1024 + t] = Hg[b * 8192 + p * 1024 + t];
  __syncthreads();

  // P3: WhC = W_att3 @ H; store EW = exp(2*WhC)
  {
    int r = t & 127, cg = t >> 7;
    const float* xb = A + cg * 8 * 128;
    const float* wp = W_att + r * 384 + 256;
    float acc[8];
#pragma unroll
    for (int i = 0; i < 8; ++i) acc[i] = 0.f;
#pragma unroll 1
    for (int k = 0; k < HN; k += 4) {
      float4 w = *(const float4*)(wp + k);
#pragma unroll
      for (int i = 0; i < 8; ++i) {
        float4 xv = *(const float4*)(xb + i * 128 + k);   // broadcast
        acc[i] = fmaf(w.x, xv.x, acc[i]);
        acc[i] = fmaf(w.y, xv.y, acc[i]);
        acc[i] = fmaf(w.z, xv.z, acc[i]);
        acc[i] = fmaf(w.w, xv.w, acc[i]);
      }
    }
#pragma unroll
    for (int i = 0; i < 8; ++i)
      WHC[(cg * 8 + i) * 128 + r] = __expf(2.0f * acc[i]);
    __syncthreads();
  }

  // P4: stage SE transposed
  for (int p = 0; p < 8; ++p) {
    int idx = p * 1024 + t;
    int h = idx >> 6, s = idx & 63;
    SET[s * 132 + h] = SE[b * 8192 + idx];
  }
  __syncthreads();

  // P5: U_t = W_att1 @ SE^T + dyn-fold; store EU = exp(2*U)
  {
    int r = t & 127, cg = t >> 7;
    const float* xb = SET + cg * 8 * 132;
    const float* wp = W_att + r * 384;
    float acc[8];
#pragma unroll
    for (int i = 0; i < 8; ++i) acc[i] = 0.f;
#pragma unroll 1
    for (int k = 0; k < HN; k += 4) {
      float4 w = *(const float4*)(wp + k);
#pragma unroll
      for (int i = 0; i < 8; ++i) {
        float4 xv = *(const float4*)(xb + i * 132 + k);   // broadcast
        acc[i] = fmaf(w.x, xv.x, acc[i]);
        acc[i] = fmaf(w.y, xv.y, acc[i]);
        acc[i] = fmaf(w.z, xv.z, acc[i]);
        acc[i] = fmaf(w.w, xv.w, acc[i]);
      }
    }
    float wd0 = WDs[2 * r], wd1 = WDs[2 * r + 1], cvv = CVs[r];
#pragma unroll
    for (int i = 0; i < 8; ++i) {
      int n = cg * 8 + i;
      UT[r * 66 + n] =
          __expf(2.0f * (acc[i] + wd0 * DY[n] + wd1 * DY[64 + n] + cvv));
    }
    __syncthreads();
  }

  // P6: scores via score = Vsum - sum_h (2 v_h) * rcp(EU*EW + 1)
  {
    int s = t & 63, slot = t >> 6;
    float vsum = sm[OFF_VS];
    float acc[4];
#pragma unroll
    for (int j = 0; j < 4; ++j) acc[j] = 0.f;
    for (int h = 0; h < HN; h += 4) {
      float u0 = UT[(h + 0) * 66 + s];
      float u1 = UT[(h + 1) * 66 + s];
      float u2 = UT[(h + 2) * 66 + s];
      float u3 = UT[(h + 3) * 66 + s];
      float4 v4 = *(const float4*)(SV + h);   // 2*v
#pragma unroll
      for (int j = 0; j < 4; ++j) {
        float4 wh = *(const float4*)(WHC + (slot * 4 + j) * 128 + h);
        float a = acc[j];
        float d0 = fmaf(u0, wh.x, 1.0f);
        float d1 = fmaf(u1, wh.y, 1.0f);
        float d2 = fmaf(u2, wh.z, 1.0f);
        float d3 = fmaf(u3, wh.w, 1.0f);
        a = fmaf(v4.x, __builtin_amdgcn_rcpf(d0), a);
        a = fmaf(v4.y, __builtin_amdgcn_rcpf(d1), a);
        a = fmaf(v4.z, __builtin_amdgcn_rcpf(d2), a);
        a = fmaf(v4.w, __builtin_amdgcn_rcpf(d3), a);
        acc[j] = a;
      }
    }
    __syncthreads();
#pragma unroll
    for (int j = 0; j < 4; ++j) A[(slot * 4 + j) * 64 + s] = vsum - acc[j];
    __syncthreads();
  }

  // P7: gumbels
  {
    float* G = A + 4096;
    for (int p = 0; p < 4; ++p) {
      int idx = p * 1024 + t;
      int i = idx >> 6;
      G[idx] = jax_gumbel(KK[2 * i], KK[2 * i + 1], b * 64 + (idx & 63));
    }
    __syncthreads();
  }

  // P8: serial sampling (wave 0), merged single tree
  if (t < 64) {
    const float* Pl = A;
    const float* Gl = A + 4096;
    int s = t;
    bool visited = false;
    for (int i = 0; i < SN; ++i) {
      float score = Pl[i * 64 + s];
      bool allowed = (i == 0) ? (s == 0) : (!visited);
      float logit = allowed ? score : NEGV;
      float z = logit + Gl[i * 64 + s];
      float bz = z; int bi = s;
      float se = expf(logit);     // scores O(1): no shift needed
#pragma unroll
      for (int off = 32; off > 0; off >>= 1) {
        float oz = __shfl_xor(bz, off);
        int oi = __shfl_xor(bi, off);
        float os = __shfl_xor(se, off);
        if (oz > bz || (oz == bz && oi < bi)) { bz = oz; bi = oi; }
        se += os;
      }
      int ptr = bi;
      float chosen = __shfl(logit, ptr);
      float logp = chosen - logf(se);
      if (s == ptr) visited = true;
      if (s == 0) {
        out[b * SN + i] = (float)ptr;
        out[BN * SN + b * SN + i] = logp;
      }
    }
  }
}

// ---------------- MEGA: full fallback (R15 structure) ----------------
__global__ __launch_bounds__(512)
__attribute__((amdgpu_waves_per_eu(2, 2)))
void mega(
    const float* __restrict__ SE, const float* __restrict__ dynamic,
    const float* __restrict__ in_w, const float* __restrict__ in_b,
    const float* __restrict__ w_ih, const float* __restrict__ b_ih,
    const float* __restrict__ w_hh, const float* __restrict__ b_hh,
    const float* __restrict__ W_att, const float* __restrict__ v_att,
    const float* __restrict__ Wd, const float* __restrict__ cv,
    float* __restrict__ out) {
  extern __shared__ float sm[];
  int b = blockIdx.x, t = threadIdx.x;
  float* A   = sm + OFF_A;
  float* GIl = sm + OFF_GI;
  float* WHC = sm + OFF_WHC;
  float* SET = sm + OFF_SET;
  float* UT  = sm + OFF_UT;
  float* HC  = sm + OFF_HC;
  uint32_t* KK = (uint32_t*)(sm + OFF_KK);
  float* SV  = sm + OFF_SV;
  float* DY  = sm + OFF_DY;
  float* WDs = sm + OFF_WD;
  float* CVs = sm + OFF_CV;

  if (t < 64) {
    uint32_t o0, o1;
    threefry2x32(0u, 42u, 0u, (uint32_t)t, o0, o1);
    KK[2 * t] = o0; KK[2 * t + 1] = o1;
  }
  if (t < 128) {
    SV[t]  = v_att[t];
    DY[t]  = dynamic[b * 128 + t];
    CVs[t] = cv[t];
    HC[t]  = SE[b * 8192 + t * 64];
  }
  if (t < 256) WDs[t] = Wd[t];
  __syncthreads();

  {
    int ml = t >> 2, ks = t & 3;
    W8 wv = ldg8_s64(in_w + ml * HN + ks * 4);
    float bib = in_b[ml];
    for (int ii = 0; ii < SN; ++ii) {
      const float* xc = HC + (ii & 1) * 128;
      float* xn = HC + ((ii + 1) & 1) * 128;
      float4 x4[8];
#pragma unroll
      for (int q = 0; q < 8; ++q)
        x4[q] = *(const float4*)(xc + q * 16 + ks * 4);
      float s = dot8(wv, x4);
      s += __shfl_xor(s, 1); s += __shfl_xor(s, 2);
      if (ks == 0) {
        float xv = s + bib;
        A[ii * 128 + ml] = xv;
        xn[ml] = xv;
      }
      __syncthreads();
    }
  }
  {
    int r = t & 127, cg = t >> 7;
    const float* xb = A + cg * 16 * 128;
    const float* w0p = w_ih + (r)       * HN;
    const float* w1p = w_ih + (r + 128) * HN;
    const float* w2p = w_ih + (r + 256) * HN;
    float acc[3][16];
#pragma unroll
    for (int g = 0; g < 3; ++g)
#pragma unroll
      for (int i = 0; i < 16; ++i) acc[g][i] = 0.f;
#pragma unroll 1
    for (int k = 0; k < HN; k += 4) {
      float4 w0 = *(const float4*)(w0p + k);
      float4 w1 = *(const float4*)(w1p + k);
      float4 w2 = *(const float4*)(w2p + k);
#pragma unroll
      for (int i = 0; i < 16; ++i) {
        float4 xv = *(const float4*)(xb + i * 128 + k);
        acc[0][i] = fmaf(w0.x, xv.x, acc[0][i]);
        acc[0][i] = fmaf(w0.y, xv.y, acc[0][i]);
        acc[0][i] = fmaf(w0.z, xv.z, acc[0][i]);
        acc[0][i] = fmaf(w0.w, xv.w, acc[0][i]);
        acc[1][i] = fmaf(w1.x, xv.x, acc[1][i]);
        acc[1][i] = fmaf(w1.y, xv.y, acc[1][i]);
        acc[1][i] = fmaf(w1.z, xv.z, acc[1][i]);
        acc[1][i] = fmaf(w1.w, xv.w, acc[1][i]);
        acc[2][i] = fmaf(w2.x, xv.x, acc[2][i]);
        acc[2][i] = fmaf(w2.y, xv.y, acc[2][i]);
        acc[2][i] = fmaf(w2.z, xv.z, acc[2][i]);
        acc[2][i] = fmaf(w2.w, xv.w, acc[2][i]);
      }
    }
    float b0 = b_ih[r], b1 = b_ih[r + 128], b2 = b_ih[r + 256];
#pragma unroll
    for (int i = 0; i < 16; ++i) {
      int n = cg * 16 + i;
      GIl[n * 384 + r]       = acc[0][i] + b0;
      GIl[n * 384 + 128 + r] = acc[1][i] + b1;
      GIl[n * 384 + 256 + r] = acc[2][i] + b2;
    }
    __syncthreads();
  }
  if (t < 256) HC[t] = 0.f;
  __syncthreads();
  {
    int ml = t >> 2, ks = t & 3;
    W8 wv0 = ldg8_s64(w_hh + (ml)       * HN + ks * 4);
    W8 wv1 = ldg8_s64(w_hh + (ml + 128) * HN + ks * 4);
    W8 wv2 = ldg8_s64(w_hh + (ml + 256) * HN + ks * 4);
    float bh0 = b_hh[ml], bh1 = b_hh[ml + 128], bh2 = b_hh[ml + 256];
    float hp = 0.f;
    for (int ii = 0; ii < SN; ++ii) {
      const float* hcr = HC + (ii & 1) * 128;
      float* hcw = HC + ((ii + 1) & 1) * 128;
      float gi0 = 0.f, gi1 = 0.f, gi2 = 0.f;
      if (ks == 0) {
        const float* gr = GIl + ii * 384;
        gi0 = gr[ml]; gi1 = gr[128 + ml]; gi2 = gr[256 + ml];
      }
      float4 x4[8];
#pragma unroll
      for (int q = 0; q < 8; ++q)
        x4[q] = *(const float4*)(hcr + q * 16 + ks * 4);
      float s0 = dot8(wv0, x4);
      float s1 = dot8(wv1, x4);
      float s2 = dot8(wv2, x4);
      s0 += __shfl_xor(s0, 1); s0 += __shfl_xor(s0, 2);
      s1 += __shfl_xor(s1, 1); s1 += __shfl_xor(s1, 2);
      s2 += __shfl_xor(s2, 1); s2 += __shfl_xor(s2, 2);
      if (ks == 0) {
        float r = fsig(gi0 + s0 + bh0);
        float z = fsig(gi1 + s1 + bh1);
        float nn = ftanh(gi2 + r * (s2 + bh2));
        float hn = (1.0f - z) * nn + z * hp;
        hcw[ml] = hn;
        A[ii * 128 + ml] = hn;
        hp = hn;
      }
      __syncthreads();
    }
  }
  {
    int r = t & 127, cg = t >> 7;
    const float* xb = A + cg * 16 * 128;
    const float* wp = W_att + r * 384 + 256;
    float acc[16];
#pragma unroll
    for (int i = 0; i < 16; ++i) acc[i] = 0.f;
#pragma unroll 1
    for (int k = 0; k < HN; k += 4) {
      float4 w = *(const float4*)(wp + k);
#pragma unroll
      for (int i = 0; i < 16; ++i) {
        float4 xv = *(const float4*)(xb + i * 128 + k);
        acc[i] = fmaf(w.x, xv.x, acc[i]);
        acc[i] = fmaf(w.y, xv.y, acc[i]);
        acc[i] = fmaf(w.z, xv.z, acc[i]);
        acc[i] = fmaf(w.w, xv.w, acc[i]);
      }
    }
#pragma unroll
    for (int i = 0; i < 16; ++i)
      WHC[(cg * 16 + i) * 128 + r] = acc[i];
    __syncthreads();
  }
  for (int p = 0; p < 16; ++p) {
    int idx = p * 512 + t;
    int h = idx >> 6, s = idx & 63;
    SET[s * 132 + h] = SE[b * 8192 + idx];
  }
  __syncthreads();
  {
    int r = t & 127, cg = t >> 7;
    const float* xb = SET + cg * 16 * 132;
    const float* wp = W_att + r * 384;
    float acc[16];
#pragma unroll
    for (int i = 0; i < 16; ++i) acc[i] = 0.f;
#pragma unroll 1
    for (int k = 0; k < HN; k += 4) {
      float4 w = *(const float4*)(wp + k);
#pragma unroll
      for (int i = 0; i < 16; ++i) {
        float4 xv = *(const float4*)(xb + i * 132 + k);
        acc[i] = fmaf(w.x, xv.x, acc[i]);
        acc[i] = fmaf(w.y, xv.y, acc[i]);
        acc[i] = fmaf(w.z, xv.z, acc[i]);
        acc[i] = fmaf(w.w, xv.w, acc[i]);
      }
    }
    float wd0 = WDs[2 * r], wd1 = WDs[2 * r + 1], cvv = CVs[r];
#pragma unroll
    for (int i = 0; i < 16; ++i) {
      int n = cg * 16 + i;
      UT[r * 66 + n] = acc[i] + wd0 * DY[n] + wd1 * DY[64 + n] + cvv;
    }
    __syncthreads();
  }
  {
    int s = t & 63, w = t >> 6;
    float acc[8];
#pragma unroll
    for (int j = 0; j < 8; ++j) acc[j] = 0.f;
    for (int h = 0; h < HN; h += 4) {
      float u0 = UT[(h + 0) * 66 + s];
      float u1 = UT[(h + 1) * 66 + s];
      float u2 = UT[(h + 2) * 66 + s];
      float u3 = UT[(h + 3) * 66 + s];
      float4 v4 = *(const float4*)(SV + h);
#pragma unroll
      for (int j = 0; j < 8; ++j) {
        float4 wh = *(const float4*)(WHC + (w * 8 + j) * 128 + h);
        float a = acc[j];
        a = fmaf(v4.x, ftanh(u0 + wh.x), a);
        a = fmaf(v4.y, ftanh(u1 + wh.y), a);
        a = fmaf(v4.z, ftanh(u2 + wh.z), a);
        a = fmaf(v4.w, ftanh(u3 + wh.w), a);
        acc[j] = a;
      }
    }
    __syncthreads();
#pragma unroll
    for (int j = 0; j < 8; ++j) A[(w * 8 + j) * 64 + s] = acc[j];
    __syncthreads();
  }
  {
    float* G = A + 4096;
    for (int p = 0; p < 8; ++p) {
      int idx = p * 512 + t;
      int i = idx >> 6;
      G[idx] = jax_gumbel(KK[2 * i], KK[2 * i + 1], b * 64 + (idx & 63));
    }
    __syncthreads();
  }
  if (t < 64) {
    const float* Pl = A;
    const float* Gl = A + 4096;
    int s = t;
    bool visited = false;
    for (int i = 0; i < SN; ++i) {
      float score = Pl[i * 64 + s];
      bool allowed = (i == 0) ? (s == 0) : (!visited);
      float logit = allowed ? score : NEGV;
      float z = logit + Gl[i * 64 + s];
      float bz = z; int bi = s;
#pragma unroll
      for (int off = 32; off > 0; off >>= 1) {
        float oz = __shfl_xor(bz, off);
        int oi = __shfl_xor(bi, off);
        if (oz > bz || (oz == bz && oi < bi)) { bz = oz; bi = oi; }
      }
      int ptr = bi;
      float m = logit;
#pragma unroll
      for (int off = 32; off > 0; off >>= 1) m = fmaxf(m, __shfl_xor(m, off));
      float e = expf(logit - m);
      float sum = e;
#pragma unroll
      for (int off = 32; off > 0; off >>= 1) sum += __shfl_xor(sum, off);
      float chosen = __shfl(logit, ptr);
      float logp = (chosen - m) - logf(sum);
      if (s == ptr) visited = true;
      if (s == 0) {
        out[b * SN + i] = (float)ptr;
        out[BN * SN + b * SN + i] = logp;
      }
    }
  }
}

// ---------------- launch ----------------
extern "C" void kernel_launch(void* const* d_in, const int* in_sizes, int n_in,
                              void* d_out, int out_size, void* d_ws, size_t ws_size,
                              hipStream_t stream) {
  const float* SE    = (const float*)d_in[1];
  const float* dynam = (const float*)d_in[2];
  const float* dyn_w = (const float*)d_in[3];
  const float* dyn_b = (const float*)d_in[4];
  const float* in_w  = (const float*)d_in[5];
  const float* in_b  = (const float*)d_in[6];
  const float* w_ih  = (const float*)d_in[7];
  const float* w_hh  = (const float*)d_in[8];
  const float* b_ih2 = (const float*)d_in[9];
  const float* b_hh  = (const float*)d_in[10];
  const float* W_att = (const float*)d_in[11];
  const float* v_att = (const float*)d_in[12];
  float* out = (float*)d_out;
  float* ws = (float*)d_ws;

  (void)hipFuncSetAttribute((const void*)mega,
                            hipFuncAttributeMaxDynamicSharedMemorySize,
                            SMEM_FLOATS * 4);
  (void)hipFuncSetAttribute((const void*)kA_front,
                            hipFuncAttributeMaxDynamicSharedMemorySize,
                            KA_FLOATS * 4);
  (void)hipFuncSetAttribute((const void*)k3_att,
                            hipFuncAttributeMaxDynamicSharedMemorySize,
                            SMEM_FLOATS * 4);

  if (ws_size >= WS_NEED) {
    float* Hg = ws + WS_HG;
    hipLaunchKernelGGL(kA_front, dim3(BN), dim3(1024), KA_FLOATS * 4, stream,
                       SE, in_w, in_b, w_ih, b_ih2, w_hh, b_hh, Hg);
    hipLaunchKernelGGL(k3_att, dim3(BN), dim3(1024), SMEM_FLOATS * 4, stream,
                       SE, dynam, dyn_w, dyn_b, W_att, v_att, Hg, out);
  } else {
    float* Wd = ws;        // 256
    float* cv = ws + 256;  // 128
    hipLaunchKernelGGL(k0_dyn, dim3(1), dim3(128), 0, stream,
                       W_att, dyn_w, dyn_b, Wd, cv);
    hipLaunchKernelGGL(mega, dim3(BN), dim3(512), SMEM_FLOATS * 4, stream,
                       SE, dynam, in_w, in_b, w_ih, b_ih2, w_hh, b_hh,
                       W_att, v_att, Wd, cv, out);
  }
}

// Round 13
// 278.226 us; speedup vs baseline: 1.2586x; 1.2586x over previous
//
#include <hip/hip_runtime.h>
#include <stdint.h>

// PointerNetwork forward, MI355X/gfx950.
// R22: R21 regressed (kA 116->189): (1) contiguous-16 LDS slices at 64B
// lane stride = 4-way bank conflict (SQ_LDS_BANK_CONFLICT 0->8.4M);
// (2) VGPR 48 < the 32-float asm slice => spilled AGAIN at 1024 thr.
// Residency is unwinnable on this toolchain; R20's 512-thr kA (VGPR 104,
// 0 conflicts, 116us) is the keeper. This round: exact R20 revert + two
// surgical k3 cuts: P6 pairwise-rcp (v0/d0+v1/d1 = (v0 d1 + v1 d0) *
// rcp(d0 d1): trans ops halved, d-products <=1e20 safe) and P8
// __expf/__logf (feeds only logp, tol 1.6e-2; argmax path untouched).
// kA + staging + P3/P5/P7 + mega fallback byte-identical to R20 (280us).
// B=256, S=64, H=128.

#define BN 256
#define SN 64
#define HN 128
#define NEGV (-1.0e9f)
#define TINYF 1.17549435e-38f

// k3 LDS layout (floats)
#define OFF_A   0
#define OFF_GI  8192
#define OFF_WHC 8192
#define OFF_SET 16384
#define OFF_UT  24832
#define OFF_HC  33280
#define OFF_KK  33536
#define OFF_SV  33664
#define OFF_DY  33792
#define OFF_WD  33920
#define OFF_CV  34176
#define OFF_VS  34304       // Vsum scalar
#define SMEM_FLOATS 34308   // 137232 B

// kA LDS layout (floats)
#define KA_A   0
#define KA_GI  8192        // 64 x 384
#define KA_HC  32768       // 256
#define KA_FLOATS 33024    // 132096 B

// ws layout (floats): [0,256) Wd, [256,384) cv (fallback only), Hg at 384
#define WS_HG   384
#define WS_NEED ((size_t)(384 + 256 * 64 * 128) * 4)

typedef float v4f __attribute__((ext_vector_type(4)));

struct W8 { v4f a, b, c, d, e, f, g, h; };

// 8 x dwordx4 at 64B stride (32 floats of a 4-way k-split row).
__device__ __forceinline__ W8 ldg8_s64(const float* p) {
  W8 r;
  asm volatile(
      "global_load_dwordx4 %0, %8, off\n\t"
      "global_load_dwordx4 %1, %8, off offset:64\n\t"
      "global_load_dwordx4 %2, %8, off offset:128\n\t"
      "global_load_dwordx4 %3, %8, off offset:192\n\t"
      "global_load_dwordx4 %4, %8, off offset:256\n\t"
      "global_load_dwordx4 %5, %8, off offset:320\n\t"
      "global_load_dwordx4 %6, %8, off offset:384\n\t"
      "global_load_dwordx4 %7, %8, off offset:448\n\t"
      "s_waitcnt vmcnt(0)"
      : "=&v"(r.a), "=&v"(r.b), "=&v"(r.c), "=&v"(r.d),
        "=&v"(r.e), "=&v"(r.f), "=&v"(r.g), "=&v"(r.h)
      : "v"(p));
  return r;
}

__device__ __forceinline__ float dot8(const W8& w, const float4* x4) {
  float a0 = 0.f, a1 = 0.f, a2 = 0.f, a3 = 0.f;
  a0 = fmaf(w.a.x, x4[0].x, a0); a1 = fmaf(w.a.y, x4[0].y, a1);
  a2 = fmaf(w.a.z, x4[0].z, a2); a3 = fmaf(w.a.w, x4[0].w, a3);
  a0 = fmaf(w.b.x, x4[1].x, a0); a1 = fmaf(w.b.y, x4[1].y, a1);
  a2 = fmaf(w.b.z, x4[1].z, a2); a3 = fmaf(w.b.w, x4[1].w, a3);
  a0 = fmaf(w.c.x, x4[2].x, a0); a1 = fmaf(w.c.y, x4[2].y, a1);
  a2 = fmaf(w.c.z, x4[2].z, a2); a3 = fmaf(w.c.w, x4[2].w, a3);
  a0 = fmaf(w.d.x, x4[3].x, a0); a1 = fmaf(w.d.y, x4[3].y, a1);
  a2 = fmaf(w.d.z, x4[3].z, a2); a3 = fmaf(w.d.w, x4[3].w, a3);
  a0 = fmaf(w.e.x, x4[4].x, a0); a1 = fmaf(w.e.y, x4[4].y, a1);
  a2 = fmaf(w.e.z, x4[4].z, a2); a3 = fmaf(w.e.w, x4[4].w, a3);
  a0 = fmaf(w.f.x, x4[5].x, a0); a1 = fmaf(w.f.y, x4[5].y, a1);
  a2 = fmaf(w.f.z, x4[5].z, a2); a3 = fmaf(w.f.w, x4[5].w, a3);
  a0 = fmaf(w.g.x, x4[6].x, a0); a1 = fmaf(w.g.y, x4[6].y, a1);
  a2 = fmaf(w.g.z, x4[6].z, a2); a3 = fmaf(w.g.w, x4[6].w, a3);
  a0 = fmaf(w.h.x, x4[7].x, a0); a1 = fmaf(w.h.y, x4[7].y, a1);
  a2 = fmaf(w.h.z, x4[7].z, a2); a3 = fmaf(w.h.w, x4[7].w, a3);
  return (a0 + a1) + (a2 + a3);
}

__device__ __forceinline__ uint32_t rotl32(uint32_t v, int d) {
  return (v << d) | (v >> (32 - d));
}

__device__ __forceinline__ void threefry2x32(uint32_t k0, uint32_t k1,
                                             uint32_t x0, uint32_t x1,
                                             uint32_t& o0, uint32_t& o1) {
  uint32_t ks2 = k0 ^ k1 ^ 0x1BD11BDAu;
  x0 += k0; x1 += k1;
  x0 += x1; x1 = rotl32(x1, 13); x1 ^= x0;
  x0 += x1; x1 = rotl32(x1, 15); x1 ^= x0;
  x0 += x1; x1 = rotl32(x1, 26); x1 ^= x0;
  x0 += x1; x1 = rotl32(x1, 6);  x1 ^= x0;
  x0 += k1; x1 += ks2 + 1u;
  x0 += x1; x1 = rotl32(x1, 17); x1 ^= x0;
  x0 += x1; x1 = rotl32(x1, 29); x1 ^= x0;
  x0 += x1; x1 = rotl32(x1, 16); x1 ^= x0;
  x0 += x1; x1 = rotl32(x1, 24); x1 ^= x0;
  x0 += ks2; x1 += k0 + 2u;
  x0 += x1; x1 = rotl32(x1, 13); x1 ^= x0;
  x0 += x1; x1 = rotl32(x1, 15); x1 ^= x0;
  x0 += x1; x1 = rotl32(x1, 26); x1 ^= x0;
  x0 += x1; x1 = rotl32(x1, 6);  x1 ^= x0;
  x0 += k0; x1 += k1 + 3u;
  x0 += x1; x1 = rotl32(x1, 17); x1 ^= x0;
  x0 += x1; x1 = rotl32(x1, 29); x1 ^= x0;
  x0 += x1; x1 = rotl32(x1, 16); x1 ^= x0;
  x0 += x1; x1 = rotl32(x1, 24); x1 ^= x0;
  x0 += k1; x1 += ks2 + 4u;
  x0 += x1; x1 = rotl32(x1, 13); x1 ^= x0;
  x0 += x1; x1 = rotl32(x1, 15); x1 ^= x0;
  x0 += x1; x1 = rotl32(x1, 26); x1 ^= x0;
  x0 += x1; x1 = rotl32(x1, 6);  x1 ^= x0;
  x0 += ks2; x1 += k0 + 5u;
  o0 = x0; o1 = x1;
}

__device__ __forceinline__ float jax_gumbel(uint32_t k0, uint32_t k1, int j) {
  uint32_t o0, o1;
  threefry2x32(k0, k1, 0u, (uint32_t)j, o0, o1);
  uint32_t bits = o0 ^ o1;
  uint32_t ub = (bits >> 9) | 0x3F800000u;
  float u = __uint_as_float(ub) - 1.0f;
  u = fmaxf(u + TINYF, TINYF);
  return -logf(-logf(u));
}

// tanh(x) = (e^{2x}-1)/(e^{2x}+1).
__device__ __forceinline__ float ftanh(float x) {
  float e = __expf(2.0f * x);
  return (e - 1.0f) * __builtin_amdgcn_rcpf(e + 1.0f);
}

__device__ __forceinline__ float fsig(float x) {
  return __builtin_amdgcn_rcpf(1.0f + __expf(-x));
}

// ---------------- K0 (fallback path only) ----------------
__global__ void k0_dyn(const float* __restrict__ W_att, const float* __restrict__ dyn_w,
                       const float* __restrict__ dyn_b, float* __restrict__ Wd,
                       float* __restrict__ cv) {
  int h = threadIdx.x;
  float w0 = 0.f, w1 = 0.f, cc = 0.f;
  for (int k = 0; k < HN; ++k) {
    float w = W_att[h * 384 + 128 + k];
    w0 = fmaf(w, dyn_w[2 * k + 0], w0);
    w1 = fmaf(w, dyn_w[2 * k + 1], w1);
    cc = fmaf(w, dyn_b[k], cc);
  }
  Wd[2 * h] = w0; Wd[2 * h + 1] = w1; cv[h] = cc;
}

// ---------------- kA: P0 + P1 + P2 fused, H -> global (R20 exact) --------
__global__ __launch_bounds__(512)
__attribute__((amdgpu_waves_per_eu(2, 2)))
void kA_front(const float* __restrict__ SE, const float* __restrict__ in_w,
              const float* __restrict__ in_b, const float* __restrict__ w_ih,
              const float* __restrict__ b_ih, const float* __restrict__ w_hh,
              const float* __restrict__ b_hh, float* __restrict__ Hg) {
  extern __shared__ float sm[];
  float* A   = sm + KA_A;
  float* GIl = sm + KA_GI;
  float* HC  = sm + KA_HC;
  int b = blockIdx.x, t = threadIdx.x;

  if (t < 128) HC[t] = SE[b * 8192 + t * 64];   // x_{-1} = SE[b,:,0]
  __syncthreads();

  // P0: x-chain. 128 ml x 4 ks
  {
    int ml = t >> 2, ks = t & 3;
    W8 wv = ldg8_s64(in_w + ml * HN + ks * 4);
    float bib = in_b[ml];
    for (int ii = 0; ii < SN; ++ii) {
      const float* xc = HC + (ii & 1) * 128;
      float* xn = HC + ((ii + 1) & 1) * 128;
      float4 x4[8];
#pragma unroll
      for (int q = 0; q < 8; ++q)
        x4[q] = *(const float4*)(xc + q * 16 + ks * 4);
      float s = dot8(wv, x4);
      s += __shfl_xor(s, 1); s += __shfl_xor(s, 2);
      if (ks == 0) {
        float xv = s + bib;
        A[ii * 128 + ml] = xv;
        xn[ml] = xv;
      }
      __syncthreads();
    }
  }

  // P1: GI = w_ih @ X + b_ih, output-stationary over k
  {
    int r = t & 127, cg = t >> 7;
    const float* xb = A + cg * 16 * 128;
    const float* w0p = w_ih + (r)       * HN;
    const float* w1p = w_ih + (r + 128) * HN;
    const float* w2p = w_ih + (r + 256) * HN;
    float acc[3][16];
#pragma unroll
    for (int g = 0; g < 3; ++g)
#pragma unroll
      for (int i = 0; i < 16; ++i) acc[g][i] = 0.f;
#pragma unroll 1
    for (int k = 0; k < HN; k += 4) {
      float4 w0 = *(const float4*)(w0p + k);
      float4 w1 = *(const float4*)(w1p + k);
      float4 w2 = *(const float4*)(w2p + k);
#pragma unroll
      for (int i = 0; i < 16; ++i) {
        float4 xv = *(const float4*)(xb + i * 128 + k);
        acc[0][i] = fmaf(w0.x, xv.x, acc[0][i]);
        acc[0][i] = fmaf(w0.y, xv.y, acc[0][i]);
        acc[0][i] = fmaf(w0.z, xv.z, acc[0][i]);
        acc[0][i] = fmaf(w0.w, xv.w, acc[0][i]);
        acc[1][i] = fmaf(w1.x, xv.x, acc[1][i]);
        acc[1][i] = fmaf(w1.y, xv.y, acc[1][i]);
        acc[1][i] = fmaf(w1.z, xv.z, acc[1][i]);
        acc[1][i] = fmaf(w1.w, xv.w, acc[1][i]);
        acc[2][i] = fmaf(w2.x, xv.x, acc[2][i]);
        acc[2][i] = fmaf(w2.y, xv.y, acc[2][i]);
        acc[2][i] = fmaf(w2.z, xv.z, acc[2][i]);
        acc[2][i] = fmaf(w2.w, xv.w, acc[2][i]);
      }
    }
    float b0 = b_ih[r], b1 = b_ih[r + 128], b2 = b_ih[r + 256];
#pragma unroll
    for (int i = 0; i < 16; ++i) {
      int n = cg * 16 + i;
      GIl[n * 384 + r]       = acc[0][i] + b0;
      GIl[n * 384 + 128 + r] = acc[1][i] + b1;
      GIl[n * 384 + 256 + r] = acc[2][i] + b2;
    }
    __syncthreads();
  }

  // P2: GRU chain; GI prefetched at loop top; h -> Hg (global)
  if (t < 256) HC[t] = 0.f;
  __syncthreads();
  {
    int ml = t >> 2, ks = t & 3;
    W8 wv0 = ldg8_s64(w_hh + (ml)       * HN + ks * 4);
    W8 wv1 = ldg8_s64(w_hh + (ml + 128) * HN + ks * 4);
    W8 wv2 = ldg8_s64(w_hh + (ml + 256) * HN + ks * 4);
    float bh0 = b_hh[ml], bh1 = b_hh[ml + 128], bh2 = b_hh[ml + 256];
    float hp = 0.f;
    for (int ii = 0; ii < SN; ++ii) {
      const float* hcr = HC + (ii & 1) * 128;
      float* hcw = HC + ((ii + 1) & 1) * 128;
      float gi0 = 0.f, gi1 = 0.f, gi2 = 0.f;
      if (ks == 0) {                      // prefetch: hides LDS latency
        const float* gr = GIl + ii * 384;
        gi0 = gr[ml]; gi1 = gr[128 + ml]; gi2 = gr[256 + ml];
      }
      float4 x4[8];
#pragma unroll
      for (int q = 0; q < 8; ++q)
        x4[q] = *(const float4*)(hcr + q * 16 + ks * 4);
      float s0 = dot8(wv0, x4);
      float s1 = dot8(wv1, x4);
      float s2 = dot8(wv2, x4);
      s0 += __shfl_xor(s0, 1); s0 += __shfl_xor(s0, 2);
      s1 += __shfl_xor(s1, 1); s1 += __shfl_xor(s1, 2);
      s2 += __shfl_xor(s2, 1); s2 += __shfl_xor(s2, 2);
      if (ks == 0) {
        float r = fsig(gi0 + s0 + bh0);
        float z = fsig(gi1 + s1 + bh1);
        float nn = ftanh(gi2 + r * (s2 + bh2));
        float hn = (1.0f - z) * nn + z * hp;
        hcw[ml] = hn;
        Hg[b * 8192 + ii * 128 + ml] = hn;
        hp = hn;
      }
      __syncthreads();
    }
  }
}

// ---------------- k3: P3..P8 at 1024 threads; exp-factored P6 ----------------
__global__ __launch_bounds__(1024)
void k3_att(const float* __restrict__ SE, const float* __restrict__ dynamic,
            const float* __restrict__ dyn_w, const float* __restrict__ dyn_b,
            const float* __restrict__ W_att, const float* __restrict__ v_att,
            const float* __restrict__ Hg, float* __restrict__ out) {
  extern __shared__ float sm[];
  int b = blockIdx.x, t = threadIdx.x;
  float* A   = sm + OFF_A;
  float* WHC = sm + OFF_WHC;
  float* SET = sm + OFF_SET;
  float* UT  = sm + OFF_UT;
  uint32_t* KK = (uint32_t*)(sm + OFF_KK);
  float* SV  = sm + OFF_SV;
  float* DY  = sm + OFF_DY;
  float* WDs = sm + OFF_WD;
  float* CVs = sm + OFF_CV;

  // staging: dyn-fold on 512 thr; SV (pre-doubled), DY; keys; Vsum wave
  if (t < 512) {
    int h = t >> 2, ks2 = t & 3;
    const float* wp = W_att + h * 384 + 128 + ks2 * 32;
    float w0 = 0.f, w1 = 0.f, cc = 0.f;
    for (int k = 0; k < 32; ++k) {
      float w = wp[k];
      int kk = ks2 * 32 + k;
      w0 = fmaf(w, dyn_w[2 * kk + 0], w0);
      w1 = fmaf(w, dyn_w[2 * kk + 1], w1);
      cc = fmaf(w, dyn_b[kk], cc);
    }
    w0 += __shfl_xor(w0, 1); w0 += __shfl_xor(w0, 2);
    w1 += __shfl_xor(w1, 1); w1 += __shfl_xor(w1, 2);
    cc += __shfl_xor(cc, 1); cc += __shfl_xor(cc, 2);
    if (ks2 == 0) { WDs[2 * h] = w0; WDs[2 * h + 1] = w1; CVs[h] = cc; }
  } else if (t < 640) {
    int tt = t - 512;
    SV[tt] = 2.0f * v_att[tt];          // pre-doubled for the rcp form
    DY[tt] = dynamic[b * 128 + tt];
  } else if (t < 704) {
    int tt = t - 640;
    uint32_t o0, o1;
    threefry2x32(0u, 42u, 0u, (uint32_t)tt, o0, o1);
    KK[2 * tt] = o0; KK[2 * tt + 1] = o1;
  } else if (t < 768) {
    int tt = t - 704;                   // one full wave: Vsum = sum(v_att)
    float v = v_att[tt] + v_att[tt + 64];
#pragma unroll
    for (int off = 32; off > 0; off >>= 1) v += __shfl_xor(v, off);
    if (tt == 0) sm[OFF_VS] = v;
  }
  for (int p = 0; p < 8; ++p)
    A[p * 1024 + t] = Hg[b * 8192 + p * 1024 + t];
  __syncthreads();

  // P3: WhC = W_att3 @ H; store EW = exp(2*WhC)
  {
    int r = t & 127, cg = t >> 7;
    const float* xb = A + cg * 8 * 128;
    const float* wp = W_att + r * 384 + 256;
    float acc[8];
#pragma unroll
    for (int i = 0; i < 8; ++i) acc[i] = 0.f;
#pragma unroll 1
    for (int k = 0; k < HN; k += 4) {
      float4 w = *(const float4*)(wp + k);
#pragma unroll
      for (int i = 0; i < 8; ++i) {
        float4 xv = *(const float4*)(xb + i * 128 + k);   // broadcast
        acc[i] = fmaf(w.x, xv.x, acc[i]);
        acc[i] = fmaf(w.y, xv.y, acc[i]);
        acc[i] = fmaf(w.z, xv.z, acc[i]);
        acc[i] = fmaf(w.w, xv.w, acc[i]);
      }
    }
#pragma unroll
    for (int i = 0; i < 8; ++i)
      WHC[(cg * 8 + i) * 128 + r] = __expf(2.0f * acc[i]);
    __syncthreads();
  }

  // P4: stage SE transposed
  for (int p = 0; p < 8; ++p) {
    int idx = p * 1024 + t;
    int h = idx >> 6, s = idx & 63;
    SET[s * 132 + h] = SE[b * 8192 + idx];
  }
  __syncthreads();

  // P5: U_t = W_att1 @ SE^T + dyn-fold; store EU = exp(2*U)
  {
    int r = t & 127, cg = t >> 7;
    const float* xb = SET + cg * 8 * 132;
    const float* wp = W_att + r * 384;
    float acc[8];
#pragma unroll
    for (int i = 0; i < 8; ++i) acc[i] = 0.f;
#pragma unroll 1
    for (int k = 0; k < HN; k += 4) {
      float4 w = *(const float4*)(wp + k);
#pragma unroll
      for (int i = 0; i < 8; ++i) {
        float4 xv = *(const float4*)(xb + i * 132 + k);   // broadcast
        acc[i] = fmaf(w.x, xv.x, acc[i]);
        acc[i] = fmaf(w.y, xv.y, acc[i]);
        acc[i] = fmaf(w.z, xv.z, acc[i]);
        acc[i] = fmaf(w.w, xv.w, acc[i]);
      }
    }
    float wd0 = WDs[2 * r], wd1 = WDs[2 * r + 1], cvv = CVs[r];
#pragma unroll
    for (int i = 0; i < 8; ++i) {
      int n = cg * 8 + i;
      UT[r * 66 + n] =
          __expf(2.0f * (acc[i] + wd0 * DY[n] + wd1 * DY[64 + n] + cvv));
    }
    __syncthreads();
  }

  // P6: scores = Vsum - sum_h (2 v_h)/(EU*EW + 1), pairwise-rcp:
  //   v0/d0 + v1/d1 = (v0*d1 + v1*d0) * rcp(d0*d1)  — trans ops halved.
  //   d in [1, ~1e10] so d0*d1 <= ~1e20 (safe), rcp arg >= 1.
  {
    int s = t & 63, slot = t >> 6;
    float vsum = sm[OFF_VS];
    float acc[4];
#pragma unroll
    for (int j = 0; j < 4; ++j) acc[j] = 0.f;
    for (int h = 0; h < HN; h += 4) {
      float u0 = UT[(h + 0) * 66 + s];
      float u1 = UT[(h + 1) * 66 + s];
      float u2 = UT[(h + 2) * 66 + s];
      float u3 = UT[(h + 3) * 66 + s];
      float4 v4 = *(const float4*)(SV + h);   // 2*v
#pragma unroll
      for (int j = 0; j < 4; ++j) {
        float4 wh = *(const float4*)(WHC + (slot * 4 + j) * 128 + h);
        float d0 = fmaf(u0, wh.x, 1.0f);
        float d1 = fmaf(u1, wh.y, 1.0f);
        float d2 = fmaf(u2, wh.z, 1.0f);
        float d3 = fmaf(u3, wh.w, 1.0f);
        float r01 = __builtin_amdgcn_rcpf(d0 * d1);
        float r23 = __builtin_amdgcn_rcpf(d2 * d3);
        float n01 = fmaf(v4.x, d1, v4.y * d0);
        float n23 = fmaf(v4.z, d3, v4.w * d2);
        acc[j] = fmaf(n01, r01, acc[j]);
        acc[j] = fmaf(n23, r23, acc[j]);
      }
    }
    __syncthreads();
#pragma unroll
    for (int j = 0; j < 4; ++j) A[(slot * 4 + j) * 64 + s] = vsum - acc[j];
    __syncthreads();
  }

  // P7: gumbels
  {
    float* G = A + 4096;
    for (int p = 0; p < 4; ++p) {
      int idx = p * 1024 + t;
      int i = idx >> 6;
      G[idx] = jax_gumbel(KK[2 * i], KK[2 * i + 1], b * 64 + (idx & 63));
    }
    __syncthreads();
  }

  // P8: serial sampling (wave 0), merged single tree. Fast exp/log are
  // safe here: they feed only logp (tol ~1.6e-2); argmax uses z only.
  if (t < 64) {
    const float* Pl = A;
    const float* Gl = A + 4096;
    int s = t;
    bool visited = false;
    for (int i = 0; i < SN; ++i) {
      float score = Pl[i * 64 + s];
      bool allowed = (i == 0) ? (s == 0) : (!visited);
      float logit = allowed ? score : NEGV;
      float z = logit + Gl[i * 64 + s];
      float bz = z; int bi = s;
      float se = __expf(logit);   // scores O(1): no shift needed
#pragma unroll
      for (int off = 32; off > 0; off >>= 1) {
        float oz = __shfl_xor(bz, off);
        int oi = __shfl_xor(bi, off);
        float os = __shfl_xor(se, off);
        if (oz > bz || (oz == bz && oi < bi)) { bz = oz; bi = oi; }
        se += os;
      }
      int ptr = bi;
      float chosen = __shfl(logit, ptr);
      float logp = chosen - __logf(se);
      if (s == ptr) visited = true;
      if (s == 0) {
        out[b * SN + i] = (float)ptr;
        out[BN * SN + b * SN + i] = logp;
      }
    }
  }
}

// ---------------- MEGA: full fallback ----------------
__global__ __launch_bounds__(512)
__attribute__((amdgpu_waves_per_eu(2, 2)))
void mega(
    const float* __restrict__ SE, const float* __restrict__ dynamic,
    const float* __restrict__ in_w, const float* __restrict__ in_b,
    const float* __restrict__ w_ih, const float* __restrict__ b_ih,
    const float* __restrict__ w_hh, const float* __restrict__ b_hh,
    const float* __restrict__ W_att, const float* __restrict__ v_att,
    const float* __restrict__ Wd, const float* __restrict__ cv,
    float* __restrict__ out) {
  extern __shared__ float sm[];
  int b = blockIdx.x, t = threadIdx.x;
  float* A   = sm + OFF_A;
  float* GIl = sm + OFF_GI;
  float* WHC = sm + OFF_WHC;
  float* SET = sm + OFF_SET;
  float* UT  = sm + OFF_UT;
  float* HC  = sm + OFF_HC;
  uint32_t* KK = (uint32_t*)(sm + OFF_KK);
  float* SV  = sm + OFF_SV;
  float* DY  = sm + OFF_DY;
  float* WDs = sm + OFF_WD;
  float* CVs = sm + OFF_CV;

  if (t < 64) {
    uint32_t o0, o1;
    threefry2x32(0u, 42u, 0u, (uint32_t)t, o0, o1);
    KK[2 * t] = o0; KK[2 * t + 1] = o1;
  }
  if (t < 128) {
    SV[t]  = v_att[t];
    DY[t]  = dynamic[b * 128 + t];
    CVs[t] = cv[t];
    HC[t]  = SE[b * 8192 + t * 64];
  }
  if (t < 256) WDs[t] = Wd[t];
  __syncthreads();

  {
    int ml = t >> 2, ks = t & 3;
    W8 wv = ldg8_s64(in_w + ml * HN + ks * 4);
    float bib = in_b[ml];
    for (int ii = 0; ii < SN; ++ii) {
      const float* xc = HC + (ii & 1) * 128;
      float* xn = HC + ((ii + 1) & 1) * 128;
      float4 x4[8];
#pragma unroll
      for (int q = 0; q < 8; ++q)
        x4[q] = *(const float4*)(xc + q * 16 + ks * 4);
      float s = dot8(wv, x4);
      s += __shfl_xor(s, 1); s += __shfl_xor(s, 2);
      if (ks == 0) {
        float xv = s + bib;
        A[ii * 128 + ml] = xv;
        xn[ml] = xv;
      }
      __syncthreads();
    }
  }
  {
    int r = t & 127, cg = t >> 7;
    const float* xb = A + cg * 16 * 128;
    const float* w0p = w_ih + (r)       * HN;
    const float* w1p = w_ih + (r + 128) * HN;
    const float* w2p = w_ih + (r + 256) * HN;
    float acc[3][16];
#pragma unroll
    for (int g = 0; g < 3; ++g)
#pragma unroll
      for (int i = 0; i < 16; ++i) acc[g][i] = 0.f;
#pragma unroll 1
    for (int k = 0; k < HN; k += 4) {
      float4 w0 = *(const float4*)(w0p + k);
      float4 w1 = *(const float4*)(w1p + k);
      float4 w2 = *(const float4*)(w2p + k);
#pragma unroll
      for (int i = 0; i < 16; ++i) {
        float4 xv = *(const float4*)(xb + i * 128 + k);
        acc[0][i] = fmaf(w0.x, xv.x, acc[0][i]);
        acc[0][i] = fmaf(w0.y, xv.y, acc[0][i]);
        acc[0][i] = fmaf(w0.z, xv.z, acc[0][i]);
        acc[0][i] = fmaf(w0.w, xv.w, acc[0][i]);
        acc[1][i] = fmaf(w1.x, xv.x, acc[1][i]);
        acc[1][i] = fmaf(w1.y, xv.y, acc[1][i]);
        acc[1][i] = fmaf(w1.z, xv.z, acc[1][i]);
        acc[1][i] = fmaf(w1.w, xv.w, acc[1][i]);
        acc[2][i] = fmaf(w2.x, xv.x, acc[2][i]);
        acc[2][i] = fmaf(w2.y, xv.y, acc[2][i]);
        acc[2][i] = fmaf(w2.z, xv.z, acc[2][i]);
        acc[2][i] = fmaf(w2.w, xv.w, acc[2][i]);
      }
    }
    float b0 = b_ih[r], b1 = b_ih[r + 128], b2 = b_ih[r + 256];
#pragma unroll
    for (int i = 0; i < 16; ++i) {
      int n = cg * 16 + i;
      GIl[n * 384 + r]       = acc[0][i] + b0;
      GIl[n * 384 + 128 + r] = acc[1][i] + b1;
      GIl[n * 384 + 256 + r] = acc[2][i] + b2;
    }
    __syncthreads();
  }
  if (t < 256) HC[t] = 0.f;
  __syncthreads();
  {
    int ml = t >> 2, ks = t & 3;
    W8 wv0 = ldg8_s64(w_hh + (ml)       * HN + ks * 4);
    W8 wv1 = ldg8_s64(w_hh + (ml + 128) * HN + ks * 4);
    W8 wv2 = ldg8_s64(w_hh + (ml + 256) * HN + ks * 4);
    float bh0 = b_hh[ml], bh1 = b_hh[ml + 128], bh2 = b_hh[ml + 256];
    float hp = 0.f;
    for (int ii = 0; ii < SN; ++ii) {
      const float* hcr = HC + (ii & 1) * 128;
      float* hcw = HC + ((ii + 1) & 1) * 128;
      float gi0 = 0.f, gi1 = 0.f, gi2 = 0.f;
      if (ks == 0) {
        const float* gr = GIl + ii * 384;
        gi0 = gr[ml]; gi1 = gr[128 + ml]; gi2 = gr[256 + ml];
      }
      float4 x4[8];
#pragma unroll
      for (int q = 0; q < 8; ++q)
        x4[q] = *(const float4*)(hcr + q * 16 + ks * 4);
      float s0 = dot8(wv0, x4);
      float s1 = dot8(wv1, x4);
      float s2 = dot8(wv2, x4);
      s0 += __shfl_xor(s0, 1); s0 += __shfl_xor(s0, 2);
      s1 += __shfl_xor(s1, 1); s1 += __shfl_xor(s1, 2);
      s2 += __shfl_xor(s2, 1); s2 += __shfl_xor(s2, 2);
      if (ks == 0) {
        float r = fsig(gi0 + s0 + bh0);
        float z = fsig(gi1 + s1 + bh1);
        float nn = ftanh(gi2 + r * (s2 + bh2));
        float hn = (1.0f - z) * nn + z * hp;
        hcw[ml] = hn;
        A[ii * 128 + ml] = hn;
        hp = hn;
      }
      __syncthreads();
    }
  }
  {
    int r = t & 127, cg = t >> 7;
    const float* xb = A + cg * 16 * 128;
    const float* wp = W_att + r * 384 + 256;
    float acc[16];
#pragma unroll
    for (int i = 0; i < 16; ++i) acc[i] = 0.f;
#pragma unroll 1
    for (int k = 0; k < HN; k += 4) {
      float4 w = *(const float4*)(wp + k);
#pragma unroll
      for (int i = 0; i < 16; ++i) {
        float4 xv = *(const float4*)(xb + i * 128 + k);
        acc[i] = fmaf(w.x, xv.x, acc[i]);
        acc[i] = fmaf(w.y, xv.y, acc[i]);
        acc[i] = fmaf(w.z, xv.z, acc[i]);
        acc[i] = fmaf(w.w, xv.w, acc[i]);
      }
    }
#pragma unroll
    for (int i = 0; i < 16; ++i)
      WHC[(cg * 16 + i) * 128 + r] = acc[i];
    __syncthreads();
  }
  for (int p = 0; p < 16; ++p) {
    int idx = p * 512 + t;
    int h = idx >> 6, s = idx & 63;
    SET[s * 132 + h] = SE[b * 8192 + idx];
  }
  __syncthreads();
  {
    int r = t & 127, cg = t >> 7;
    const float* xb = SET + cg * 16 * 132;
    const float* wp = W_att + r * 384;
    float acc[16];
#pragma unroll
    for (int i = 0; i < 16; ++i) acc[i] = 0.f;
#pragma unroll 1
    for (int k = 0; k < HN; k += 4) {
      float4 w = *(const float4*)(wp + k);
#pragma unroll
      for (int i = 0; i < 16; ++i) {
        float4 xv = *(const float4*)(xb + i * 132 + k);
        acc[i] = fmaf(w.x, xv.x, acc[i]);
        acc[i] = fmaf(w.y, xv.y, acc[i]);
        acc[i] = fmaf(w.z, xv.z, acc[i]);
        acc[i] = fmaf(w.w, xv.w, acc[i]);
      }
    }
    float wd0 = WDs[2 * r], wd1 = WDs[2 * r + 1], cvv = CVs[r];
#pragma unroll
    for (int i = 0; i < 16; ++i) {
      int n = cg * 16 + i;
      UT[r * 66 + n] = acc[i] + wd0 * DY[n] + wd1 * DY[64 + n] + cvv;
    }
    __syncthreads();
  }
  {
    int s = t & 63, w = t >> 6;
    float acc[8];
#pragma unroll
    for (int j = 0; j < 8; ++j) acc[j] = 0.f;
    for (int h = 0; h < HN; h += 4) {
      float u0 = UT[(h + 0) * 66 + s];
      float u1 = UT[(h + 1) * 66 + s];
      float u2 = UT[(h + 2) * 66 + s];
      float u3 = UT[(h + 3) * 66 + s];
      float4 v4 = *(const float4*)(SV + h);
#pragma unroll
      for (int j = 0; j < 8; ++j) {
        float4 wh = *(const float4*)(WHC + (w * 8 + j) * 128 + h);
        float a = acc[j];
        a = fmaf(v4.x, ftanh(u0 + wh.x), a);
        a = fmaf(v4.y, ftanh(u1 + wh.y), a);
        a = fmaf(v4.z, ftanh(u2 + wh.z), a);
        a = fmaf(v4.w, ftanh(u3 + wh.w), a);
        acc[j] = a;
      }
    }
    __syncthreads();
#pragma unroll
    for (int j = 0; j < 8; ++j) A[(w * 8 + j) * 64 + s] = acc[j];
    __syncthreads();
  }
  {
    float* G = A + 4096;
    for (int p = 0; p < 8; ++p) {
      int idx = p * 512 + t;
      int i = idx >> 6;
      G[idx] = jax_gumbel(KK[2 * i], KK[2 * i + 1], b * 64 + (idx & 63));
    }
    __syncthreads();
  }
  if (t < 64) {
    const float* Pl = A;
    const float* Gl = A + 4096;
    int s = t;
    bool visited = false;
    for (int i = 0; i < SN; ++i) {
      float score = Pl[i * 64 + s];
      bool allowed = (i == 0) ? (s == 0) : (!visited);
      float logit = allowed ? score : NEGV;
      float z = logit + Gl[i * 64 + s];
      float bz = z; int bi = s;
#pragma unroll
      for (int off = 32; off > 0; off >>= 1) {
        float oz = __shfl_xor(bz, off);
        int oi = __shfl_xor(bi, off);
        if (oz > bz || (oz == bz && oi < bi)) { bz = oz; bi = oi; }
      }
      int ptr = bi;
      float m = logit;
#pragma unroll
      for (int off = 32; off > 0; off >>= 1) m = fmaxf(m, __shfl_xor(m, off));
      float e = expf(logit - m);
      float sum = e;
#pragma unroll
      for (int off = 32; off > 0; off >>= 1) sum += __shfl_xor(sum, off);
      float chosen = __shfl(logit, ptr);
      float logp = (chosen - m) - logf(sum);
      if (s == ptr) visited = true;
      if (s == 0) {
        out[b * SN + i] = (float)ptr;
        out[BN * SN + b * SN + i] = logp;
      }
    }
  }
}

// ---------------- launch ----------------
extern "C" void kernel_launch(void* const* d_in, const int* in_sizes, int n_in,
                              void* d_out, int out_size, void* d_ws, size_t ws_size,
                              hipStream_t stream) {
  const float* SE    = (const float*)d_in[1];
  const float* dynam = (const float*)d_in[2];
  const float* dyn_w = (const float*)d_in[3];
  const float* dyn_b = (const float*)d_in[4];
  const float* in_w  = (const float*)d_in[5];
  const float* in_b  = (const float*)d_in[6];
  const float* w_ih  = (const float*)d_in[7];
  const float* w_hh  = (const float*)d_in[8];
  const float* b_ih2 = (const float*)d_in[9];
  const float* b_hh  = (const float*)d_in[10];
  const float* W_att = (const float*)d_in[11];
  const float* v_att = (const float*)d_in[12];
  float* out = (float*)d_out;
  float* ws = (float*)d_ws;

  (void)hipFuncSetAttribute((const void*)mega,
                            hipFuncAttributeMaxDynamicSharedMemorySize,
                            SMEM_FLOATS * 4);
  (void)hipFuncSetAttribute((const void*)kA_front,
                            hipFuncAttributeMaxDynamicSharedMemorySize,
                            KA_FLOATS * 4);
  (void)hipFuncSetAttribute((const void*)k3_att,
                            hipFuncAttributeMaxDynamicSharedMemorySize,
                            SMEM_FLOATS * 4);

  if (ws_size >= WS_NEED) {
    float* Hg = ws + WS_HG;
    hipLaunchKernelGGL(kA_front, dim3(BN), dim3(512), KA_FLOATS * 4, stream,
                       SE, in_w, in_b, w_ih, b_ih2, w_hh, b_hh, Hg);
    hipLaunchKernelGGL(k3_att, dim3(BN), dim3(1024), SMEM_FLOATS * 4, stream,
                       SE, dynam, dyn_w, dyn_b, W_att, v_att, Hg, out);
  } else {
    float* Wd = ws;        // 256
    float* cv = ws + 256;  // 128
    hipLaunchKernelGGL(k0_dyn, dim3(1), dim3(128), 0, stream,
                       W_att, dyn_w, dyn_b, Wd, cv);
    hipLaunchKernelGGL(mega, dim3(BN), dim3(512), SMEM_FLOATS * 4, stream,
                       SE, dynam, in_w, in_b, w_ih, b_ih2, w_hh, b_hh,
                       W_att, v_att, Wd, cv, out);
  }
}